// Round 1
// baseline (94.362 us; speedup 1.0000x reference)
//
#include <hip/hip_runtime.h>
#include <cstdint>
#include <cstddef>

typedef short short8 __attribute__((ext_vector_type(8)));
typedef float f32x4 __attribute__((ext_vector_type(4)));

#define NB 2
#define NC 2048
#define NE 1024
#define NH 16
#define ND 64
#define QSZ (NB*NH*NC*ND)   /* 4194304 elems per tensor (q, k, or v) */

typedef const __attribute__((address_space(1))) void GV;
typedef __attribute__((address_space(3))) void LV;

__device__ __forceinline__ unsigned short f32_to_bf16(float f) {
    union { float f; unsigned u; } v; v.f = f;
    return (unsigned short)((v.u + 0x7fffu + ((v.u >> 16) & 1u)) >> 16);
}

// One kernel for all preprocessing: f32->bf16 casts of x / wqkv / wout
// (8192 blocks) + per-batch pad length reduction (2 trailing blocks).
__global__ __launch_bounds__(256) void fused_cast_kernel(
    const float* __restrict__ x, const float* __restrict__ wqkv,
    const float* __restrict__ wout, const void* __restrict__ pad,
    unsigned short* __restrict__ x_bf, unsigned short* __restrict__ wqkv_bf,
    unsigned short* __restrict__ wout_bf, int* __restrict__ lengths)
{
    const int bid = blockIdx.x, tid = threadIdx.x;
    if (bid < 8192) {
        const float* src; unsigned short* dst; int i;
        if (bid < 4096)      { src = x;    dst = x_bf;    i = bid*256 + tid; }
        else if (bid < 7168) { src = wqkv; dst = wqkv_bf; i = (bid-4096)*256 + tid; }
        else                 { src = wout; dst = wout_bf; i = (bid-7168)*256 + tid; }
        float4 v = ((const float4*)src)[i];
        ushort4 o;
        o.x = f32_to_bf16(v.x); o.y = f32_to_bf16(v.y);
        o.z = f32_to_bf16(v.z); o.w = f32_to_bf16(v.w);
        ((ushort4*)dst)[i] = o;
    } else {
        // pad_mask is monotone (arange < length) -> count valids = length.
        const int b = bid - 8192;
        unsigned w0 = ((const unsigned*)pad)[0];
        int cnt = 0;
        for (int i = tid; i < NC; i += 256) {
            int idx = b*NC + i;
            bool valid;
            if (w0 == 1u)               valid = ((const int*)pad)[idx] != 0;
            else if (w0 == 0x3f800000u) valid = ((const float*)pad)[idx] != 0.0f;
            else                        valid = ((const unsigned char*)pad)[idx] != 0;
            cnt += valid ? 1 : 0;
        }
        cnt += __shfl_xor(cnt, 1);  cnt += __shfl_xor(cnt, 2);
        cnt += __shfl_xor(cnt, 4);  cnt += __shfl_xor(cnt, 8);
        cnt += __shfl_xor(cnt, 16); cnt += __shfl_xor(cnt, 32);
        __shared__ int ws_[4];
        if ((tid & 63) == 0) ws_[tid >> 6] = cnt;
        __syncthreads();
        if (tid == 0) lengths[b] = ws_[0] + ws_[1] + ws_[2] + ws_[3];
    }
}

// ---------------------------------------------------------------------------
// QKV GEMM, deep-pipelined (8-phase-per-2-tiles class schedule, counted vmcnt).
// C = A[4096,1024] * Bw[3072,1024]^T + bias, bf16 scatter epilogue into qkv.
// BM=256 x BN=192, BK=64 -> grid 16x16 = 256 blocks = exactly 1 block/CU.
// 512 threads = 8 waves as 2(M) x 4(N); per-wave 128x48 = acc[8][3] (96 VGPR).
// LDS 112 KiB: As[2][256*64], Bs[2][192*64], XOR-swizzled (chunk ^= row&7) via
// pre-swizzled global source + swizzled ds_read (same involution as before).
// Phase = (M-half, K-half): 12 MFMA each, 2 raw s_barriers, setprio around MFMA.
// Prefetch next K-tile into the OTHER buffer (WAR-free): ph1 issues B (3 loads),
// ph2 issues A units {0,2} (= rows read by mh0 next iter), ph3 issues A {1,3}.
// Counted waits (per-wave FIFO, m135 semantics):
//   ph1: vmcnt(3)  -> this tile's A{1,3} landed (leaves 3 B' in flight)
//   ph4: vmcnt(2)  -> next tile's B + A{0,2} landed (leaves A'{1,3} in flight)
// vmcnt never drains to 0 in the main loop.
// ---------------------------------------------------------------------------
__global__ __launch_bounds__(512, 2) void gemm_qkv_kernel(
    const unsigned short* __restrict__ A,
    const unsigned short* __restrict__ Bw,
    const float* __restrict__ bias,
    unsigned short* __restrict__ outQ)
{
    constexpr int K = 1024;
    __shared__ unsigned short As[2][256*64];
    __shared__ unsigned short Bs[2][192*64];
    const int tid = threadIdx.x;
    const int w = tid >> 6, lane = tid & 63;
    const int wr = w >> 2, wc = w & 3;          // 2 x 4 wave grid
    const int g = lane >> 4, lr = lane & 15;
    const int id = blockIdx.x;                   // 256 blocks, nwg%8==0
    const int swz = (id & 7) * 32 + (id >> 3);   // bijective XCD swizzle
    const int mBase = (swz >> 4) * 256, nBase = (swz & 15) * 192;

    f32x4 acc[8][3];
#pragma unroll
    for (int m = 0; m < 8; ++m)
#pragma unroll
        for (int n = 0; n < 3; ++n) acc[m][n] = (f32x4){0.f, 0.f, 0.f, 0.f};

    // staging geometry: unit j = 8KB = 64 LDS rows; wave w owns 1KB segment.
    // LDS dest linear; global source pre-swizzled (chunk ^ row&7).
    int srw[4], sck[4]; unsigned ldso[4];
#pragma unroll
    for (int j = 0; j < 4; ++j) {
        int o = ((j*8 + w) << 10) + lane*16;
        int row = o >> 7;
        int chunk = ((o >> 4) & 7) ^ (row & 7);
        srw[j] = row; sck[j] = chunk * 8; ldso[j] = (unsigned)((j*8 + w) << 10);
    }
    const unsigned short* Abase = A  + (size_t)mBase * K;
    const unsigned short* Bbase = Bw + (size_t)nBase * K;

#define QISS_B(kt, buf) do { _Pragma("unroll")                                    \
    for (int j = 0; j < 3; ++j) {                                                 \
        const unsigned short* gb = Bbase + (size_t)srw[j]*K + ((kt)<<6) + sck[j]; \
        __builtin_amdgcn_global_load_lds((GV*)gb, (LV*)((char*)Bs[buf] + ldso[j]), 16, 0, 0); \
    } } while (0)
#define QISS_A2(kt, buf, j0, j1) do {                                             \
        const unsigned short* g0 = Abase + (size_t)srw[j0]*K + ((kt)<<6) + sck[j0]; \
        __builtin_amdgcn_global_load_lds((GV*)g0, (LV*)((char*)As[buf] + ldso[j0]), 16, 0, 0); \
        const unsigned short* g1 = Abase + (size_t)srw[j1]*K + ((kt)<<6) + sck[j1]; \
        __builtin_amdgcn_global_load_lds((GV*)g1, (LV*)((char*)As[buf] + ldso[j1]), 16, 0, 0); \
    } while (0)
#define QRD_B(buf, ks) do { _Pragma("unroll")                                     \
    for (int n = 0; n < 3; ++n) {                                                 \
        int row = wc*48 + n*16 + lr;                                              \
        int chunk = ((ks)*4 + g) ^ (row & 7);                                     \
        bf[n] = *(const short8*)((const char*)Bs[buf] + row*128 + chunk*16);      \
    } } while (0)
#define QRD_A(buf, ks, mh) do { _Pragma("unroll")                                 \
    for (int m = 0; m < 4; ++m) {                                                 \
        int row = wr*128 + (mh)*64 + m*16 + lr;                                   \
        int chunk = ((ks)*4 + g) ^ (row & 7);                                     \
        af[m] = *(const short8*)((const char*)As[buf] + row*128 + chunk*16);      \
    } } while (0)
#define QMM(mh) do { _Pragma("unroll")                                            \
    for (int m = 0; m < 4; ++m) { _Pragma("unroll")                               \
    for (int n = 0; n < 3; ++n)                                                   \
        acc[(mh)*4+m][n] = __builtin_amdgcn_mfma_f32_16x16x32_bf16(af[m], bf[n], acc[(mh)*4+m][n], 0, 0, 0); \
    } } while (0)
#define QBAR __builtin_amdgcn_s_barrier()

    short8 af[4], bf[3];

    // prologue: tile 0 -> buf0, issue order B0 B1 B2 A0 A2 A1 A3
    QISS_B(0, 0); QISS_A2(0, 0, 0, 2); QISS_A2(0, 0, 1, 3);
    asm volatile("s_waitcnt vmcnt(2)" ::: "memory");   // B,A0,A2 of tile 0 landed
    QBAR;

    for (int kt = 0; kt < 15; ++kt) {
        const int b = kt & 1, b1 = b ^ 1;
        // ph1: (mh0, ks0); prefetch next-tile B
        QRD_B(b, 0); QRD_A(b, 0, 0);
        QISS_B(kt + 1, b1);
        asm volatile("s_waitcnt vmcnt(3)" ::: "memory");   // this tile's A1,A3
        QBAR;
        __builtin_amdgcn_s_setprio(1); QMM(0); __builtin_amdgcn_s_setprio(0);
        QBAR;
        // ph2: (mh1, ks0); prefetch next-tile A units {0,2}
        QRD_A(b, 0, 1);
        QISS_A2(kt + 1, b1, 0, 2);
        QBAR;
        __builtin_amdgcn_s_setprio(1); QMM(1); __builtin_amdgcn_s_setprio(0);
        QBAR;
        // ph3: (mh0, ks1); prefetch next-tile A units {1,3}
        QRD_B(b, 1); QRD_A(b, 1, 0);
        QISS_A2(kt + 1, b1, 1, 3);
        QBAR;
        __builtin_amdgcn_s_setprio(1); QMM(0); __builtin_amdgcn_s_setprio(0);
        QBAR;
        // ph4: (mh1, ks1); ensure next tile's B,A0,A2 landed for next ph1
        QRD_A(b, 1, 1);
        asm volatile("s_waitcnt vmcnt(2)" ::: "memory");
        QBAR;
        __builtin_amdgcn_s_setprio(1); QMM(1); __builtin_amdgcn_s_setprio(0);
        QBAR;
    }
    // tail: tile 15 in buf1, no prefetch, drain remaining A1,A3
    QRD_B(1, 0); QRD_A(1, 0, 0);
    asm volatile("s_waitcnt vmcnt(0)" ::: "memory");
    QBAR;
    QMM(0);
    QRD_A(1, 0, 1); QMM(1);
    QRD_B(1, 1); QRD_A(1, 1, 0); QMM(0);
    QRD_A(1, 1, 1); QMM(1);

#undef QISS_B
#undef QISS_A2
#undef QRD_B
#undef QRD_A
#undef QMM
#undef QBAR

    // Epilogue.  C/D layout: col = lane&15 (B side), row = 4*(lane>>4)+reg (A).
    // Columns of a BN=192 tile can straddle the Q/K|V boundary (2048) -> branch
    // per n-frag (boundary 16-aligned, so uniform within the 16-col span).
#pragma unroll
    for (int n = 0; n < 3; ++n) {
        const int colb = nBase + wc*48 + n*16;
        const int col = colb + lr;
        const float bv = bias[col];
        if (colb >= 2048) {
            // V path: pi-permuted transposed layout, 8B packed stores.
            const int hh = (col >> 6) & 15, d = col & 63;
#pragma unroll
            for (int m = 0; m < 8; ++m) {
                int rowb = mBase + wr*128 + m*16 + 4*g;     // token index, r=0
                int bb = rowb >> 11, c = rowb & 2047;
                int mq = m & 3;                              // pi within 64-group
                int cp = (c & ~63) | ((mq >> 1) << 5) | (g << 3) | ((mq & 1) << 2);
                size_t base = (((size_t)((4 + bb)*16 + hh))*64 + d)*2048 + cp;
                float v0 = acc[m][n][0] + bv, v1 = acc[m][n][1] + bv;
                float v2 = acc[m][n][2] + bv, v3 = acc[m][n][3] + bv;
                unsigned w0, w1;
                asm("v_cvt_pk_bf16_f32 %0, %1, %2" : "=v"(w0) : "v"(v0), "v"(v1));
                asm("v_cvt_pk_bf16_f32 %0, %1, %2" : "=v"(w1) : "v"(v2), "v"(v3));
                union { unsigned u[2]; uint2 v; } pk2; pk2.u[0] = w0; pk2.u[1] = w1;
                *(uint2*)(outQ + base) = pk2.v;
            }
        } else {
            // Q/K path (Q pre-scaled into exp2 domain: 0.125 * log2(e)).
            const int t = col >> 10, hh = (col >> 6) & 15, d = col & 63;
            const float qscale = (t == 0) ? 0.1803368801f : 1.0f;
#pragma unroll
            for (int m = 0; m < 8; ++m) {
                int rowb = mBase + wr*128 + m*16 + 4*g;
#pragma unroll
                for (int r = 0; r < 4; ++r) {
                    int row = rowb + r;               // = b*NC + c
                    int bb = row >> 11, c = row & 2047;
                    unsigned short bf16v = f32_to_bf16((acc[m][n][r] + bv) * qscale);
                    size_t idx = ((((size_t)(t*2 + bb))*16 + hh)*2048 + c)*64 + d;
                    outQ[idx] = bf16v;
                }
            }
        }
    }
}

// C = A[M,K] * Bw[N,K]^T + bias.  Tile TM x 128, BK=64, 4 waves, 16x16x32 MFMA.
// TM=64:  waves 1x4 own 64x32 (out-proj: 512 blocks -> 2/CU).
// 1-D grid with bijective XCD swizzle (nwg % 8 == 0).
// EPI=0: f32 out [M,N].
template<int EPI, int TM, int WPE>
__global__ __launch_bounds__(256, WPE) void gemm_bt_kernel(
    const unsigned short* __restrict__ A,
    const unsigned short* __restrict__ Bw,
    const float* __restrict__ bias,
    float* __restrict__ outF,
    unsigned short* __restrict__ outQ,
    int M, int N, int K)
{
    constexpr int NF = (TM == 128) ? 4 : 2;       // n-frags per wave
    constexpr int WCW = 16 * NF;                  // cols per wave
    __shared__ unsigned short As[TM*64];
    __shared__ unsigned short Bs[128*64];
    const int tid = threadIdx.x;
    const int w = tid >> 6, lane = tid & 63;
    const int wr = (TM == 128) ? (w >> 1) : 0;
    const int wc = (TM == 128) ? (w & 1) : w;
    const int g = lane >> 4, lr = lane & 15;
    const int nbx = N >> 7, nwg = gridDim.x;
    const int id = blockIdx.x;
    const int swz = (id & 7) * (nwg >> 3) + (id >> 3);
    const int mBase = (swz / nbx) * TM, nBase = (swz % nbx) * 128;

    f32x4 acc[4][NF];
#pragma unroll
    for (int m = 0; m < 4; ++m)
#pragma unroll
        for (int n = 0; n < NF; ++n) acc[m][n] = (f32x4){0.f, 0.f, 0.f, 0.f};

    constexpr int AJ = TM / 32;                   // A staging instrs (1KB each)
    int srow[4], scol[4]; unsigned ldso[4];
#pragma unroll
    for (int j = 0; j < 4; ++j) {
        int o = ((j*4 + w) << 10) + lane*16;
        int row = o >> 7;
        int chunk = ((o >> 4) & 7) ^ (row & 7);
        srow[j] = row; scol[j] = chunk * 8; ldso[j] = (unsigned)((j*4 + w) << 10);
    }

    const int nk = K >> 6;
    for (int kt = 0; kt < nk; ++kt) {
        const int k0 = kt << 6;
#pragma unroll
        for (int j = 0; j < AJ; ++j) {
            const unsigned short* ga = A + (size_t)(mBase + srow[j])*K + (k0 + scol[j]);
            __builtin_amdgcn_global_load_lds((GV*)ga, (LV*)((char*)As + ldso[j]), 16, 0, 0);
        }
#pragma unroll
        for (int j = 0; j < 4; ++j) {
            const unsigned short* gb = Bw + (size_t)(nBase + srow[j])*K + (k0 + scol[j]);
            __builtin_amdgcn_global_load_lds((GV*)gb, (LV*)((char*)Bs + ldso[j]), 16, 0, 0);
        }
        __syncthreads();
#pragma unroll
        for (int ks = 0; ks < 2; ++ks) {
            short8 af[4], bf[NF];
#pragma unroll
            for (int m = 0; m < 4; ++m) {
                int row = wr*64 + m*16 + lr;
                int chunk = (ks*4 + g) ^ (row & 7);
                af[m] = *(const short8*)((const char*)As + row*128 + chunk*16);
            }
#pragma unroll
            for (int n = 0; n < NF; ++n) {
                int row = wc*WCW + n*16 + lr;
                int chunk = (ks*4 + g) ^ (row & 7);
                bf[n] = *(const short8*)((const char*)Bs + row*128 + chunk*16);
            }
#pragma unroll
            for (int m = 0; m < 4; ++m)
#pragma unroll
                for (int n = 0; n < NF; ++n)
                    acc[m][n] = __builtin_amdgcn_mfma_f32_16x16x32_bf16(af[m], bf[n], acc[m][n], 0, 0, 0);
        }
        __syncthreads();
    }

    // Epilogue.  C/D layout: col = lane&15, row = 4*(lane>>4)+reg.
    if constexpr (EPI == 0) {
#pragma unroll
        for (int n = 0; n < NF; ++n) {
            int col = nBase + wc*WCW + n*16 + lr;
            float bv = bias[col];
#pragma unroll
            for (int m = 0; m < 4; ++m) {
                int rowb = mBase + wr*64 + m*16 + 4*g;
#pragma unroll
                for (int r = 0; r < 4; ++r)
                    outF[(size_t)(rowb + r)*N + col] = acc[m][n][r] + bv;
            }
        }
    } else {
        if (nBase >= 2048) {
            // V path: pi-permuted transposed layout, 8B packed stores.
#pragma unroll
            for (int n = 0; n < NF; ++n) {
                int col = nBase + wc*WCW + n*16 + lr;
                float bv = bias[col];
                int hh = (col >> 6) & 15, d = col & 63;
#pragma unroll
                for (int m = 0; m < 4; ++m) {
                    int rowb = mBase + wr*64 + m*16 + 4*g;     // token index, r=0
                    int bb = rowb >> 11, c = rowb & 2047;
                    int cp = (c & ~63) | ((m >> 1) << 5) | (g << 3) | ((m & 1) << 2);
                    size_t base = (((size_t)((4 + bb)*16 + hh))*64 + d)*2048 + cp;
                    float v0 = acc[m][n][0] + bv, v1 = acc[m][n][1] + bv;
                    float v2 = acc[m][n][2] + bv, v3 = acc[m][n][3] + bv;
                    unsigned w0, w1;
                    asm("v_cvt_pk_bf16_f32 %0, %1, %2" : "=v"(w0) : "v"(v0), "v"(v1));
                    asm("v_cvt_pk_bf16_f32 %0, %1, %2" : "=v"(w1) : "v"(v2), "v"(v3));
                    union { unsigned u[2]; uint2 v; } pk2; pk2.u[0] = w0; pk2.u[1] = w1;
                    *(uint2*)(outQ + base) = pk2.v;
                }
            }
        } else {
            // Q/K path (Q pre-scaled into exp2 domain: 0.125 * log2(e)).
#pragma unroll
            for (int n = 0; n < NF; ++n) {
                int col = nBase + wc*WCW + n*16 + lr;
                float bv = bias[col];
                int t = col >> 10, hh = (col >> 6) & 15, d = col & 63;
                float qscale = (t == 0) ? 0.1803368801f : 1.0f;
#pragma unroll
                for (int m = 0; m < 4; ++m) {
                    int rowb = mBase + wr*64 + m*16 + 4*g;
#pragma unroll
                    for (int r = 0; r < 4; ++r) {
                        int row = rowb + r;               // = b*NC + c
                        int bb = row >> 11, c = row & 2047;
                        unsigned short bf16v = f32_to_bf16((acc[m][n][r] + bv) * qscale);
                        size_t idx = ((((size_t)(t*2 + bb))*16 + hh)*2048 + c)*64 + d;
                        outQ[idx] = bf16v;
                    }
                }
            }
        }
    }
}

// Flash attention, causal, swapped-QK^T (one q-row per lane), in-register P.
// One q-tile per block; 1024 blocks = 4/CU; qb<->y permutation gives constant
// per-CU-quad work.  Row-sum l computed ON THE MFMA PIPE via mfma(P, ones) --
// acc_l[r] lands in the same C/D indexing as oa (row 4g+r), so no shuffles,
// no per-tile VALU adds.  No exp clamp (scores are bounded dot-products).
__global__ __launch_bounds__(256, 4) void attn_kernel(
    const unsigned short* __restrict__ qkv,
    const int* __restrict__ lengths,
    unsigned short* __restrict__ ctx)
{
    __shared__ unsigned short Kt[2][64*64];
    __shared__ unsigned short Vt[2][64*64];
    const int bh = blockIdx.x;
    const int b = bh >> 4, h = bh & 15;
    const int y = blockIdx.y;
    const int qb = (y < 8) ? 31 - y : (y < 16) ? y - 8 : (y < 24) ? 39 - y : y - 16;
    const int q0 = qb * 64;
    const int len = lengths[b];
    const int nt = min(qb + 1, (len + 63) >> 6);
    const int tid = threadIdx.x, w = tid >> 6, lane = tid & 63;
    const int g = lane >> 4, lr = lane & 15;
    const unsigned short* qp = qkv +          ((size_t)(b*NH + h))*NC*ND;
    const unsigned short* kp = qkv + QSZ    + ((size_t)(b*NH + h))*NC*ND;
    const unsigned short* vp = qkv + 2*QSZ  + ((size_t)(b*NH + h))*ND*NC;  // [d][c-perm]
    const int qw0 = q0 + w*16;

    short8 aq[2];
#pragma unroll
    for (int ks = 0; ks < 2; ++ks)
        aq[ks] = *(const short8*)(qp + (size_t)(qw0 + lr)*ND + ks*32 + 8*g);

    f32x4 oa[4];
#pragma unroll
    for (int n = 0; n < 4; ++n) oa[n] = (f32x4){0.f, 0.f, 0.f, 0.f};
    f32x4 acc_l = (f32x4){0.f, 0.f, 0.f, 0.f};
    union { unsigned u[4]; short8 s; } ones;
    ones.u[0] = ones.u[1] = ones.u[2] = ones.u[3] = 0x3F803F80u;   // bf16 1.0 x8

    // staging geometry (per-lane invariant)
    int srw[2], sck[2]; unsigned ldso[2];
#pragma unroll
    for (int j = 0; j < 2; ++j) {
        int o = ((j*4 + w) << 10) + lane*16;
        int row = o >> 7;
        int chunk = ((o >> 4) & 7) ^ (row & 7);
        srw[j] = row; sck[j] = chunk * 8; ldso[j] = (unsigned)((j*4 + w) << 10);
    }

#define STAGE(T, BUF) do {                                                        \
    int k0s = (T) << 6;                                                           \
    _Pragma("unroll")                                                             \
    for (int j = 0; j < 2; ++j) {                                                 \
        const unsigned short* gk = kp + (size_t)(k0s + srw[j])*ND + sck[j];       \
        const unsigned short* gv = vp + (size_t)srw[j]*NC + k0s + sck[j];         \
        __builtin_amdgcn_global_load_lds((GV*)gk, (LV*)((char*)Kt[BUF] + ldso[j]), 16, 0, 0); \
        __builtin_amdgcn_global_load_lds((GV*)gv, (LV*)((char*)Vt[BUF] + ldso[j]), 16, 0, 0); \
    } } while (0)

    STAGE(0, 0);
    __syncthreads();

#pragma unroll 2
    for (int t = 0; t < nt; ++t) {
        if (t + 1 < nt) STAGE(t + 1, (t + 1) & 1);
        const char* Kb = (const char*)Kt[t & 1];
        const char* Vb = (const char*)Vt[t & 1];
        const int k0 = t << 6;

        // S^T: mfma(A=K, B=Q).  sa[a][r] = S[key=k0+16a+4g+r][q=qw0+lr]
        f32x4 sa[4];
#pragma unroll
        for (int a = 0; a < 4; ++a) sa[a] = (f32x4){0.f, 0.f, 0.f, 0.f};
        __builtin_amdgcn_s_setprio(1);
#pragma unroll
        for (int ks = 0; ks < 2; ++ks) {
#pragma unroll
            for (int a = 0; a < 4; ++a) {
                int row = a*16 + lr;
                int chunk = (ks*4 + g) ^ (row & 7);
                short8 ak = *(const short8*)(Kb + row*128 + chunk*16);
                sa[a] = __builtin_amdgcn_mfma_f32_16x16x32_bf16(ak, aq[ks], sa[a], 0, 0, 0);
            }
        }
        __builtin_amdgcn_s_setprio(0);

        // no-max softmax in exp2 domain (no clamp: scores are bounded)
        float p[4][4];
        const bool edge = (t == nt - 1);
        if (!edge) {
#pragma unroll
            for (int a = 0; a < 4; ++a)
#pragma unroll
                for (int r = 0; r < 4; ++r)
                    p[a][r] = exp2f(sa[a][r]);
        } else {
            const int qg = qw0 + lr;
            const int kb0 = k0 + 4*g;
#pragma unroll
            for (int a = 0; a < 4; ++a)
#pragma unroll
                for (int r = 0; r < 4; ++r) {
                    int key = kb0 + 16*a + r;
                    p[a][r] = (key <= qg && key < len) ? exp2f(sa[a][r]) : 0.f;
                }
        }

        // pack P to bf16 fragments in-register (kappa ordering)
        unsigned pw0, pw1, pw2, pw3, pw4, pw5, pw6, pw7;
        asm("v_cvt_pk_bf16_f32 %0, %1, %2" : "=v"(pw0) : "v"(p[0][0]), "v"(p[0][1]));
        asm("v_cvt_pk_bf16_f32 %0, %1, %2" : "=v"(pw1) : "v"(p[0][2]), "v"(p[0][3]));
        asm("v_cvt_pk_bf16_f32 %0, %1, %2" : "=v"(pw2) : "v"(p[1][0]), "v"(p[1][1]));
        asm("v_cvt_pk_bf16_f32 %0, %1, %2" : "=v"(pw3) : "v"(p[1][2]), "v"(p[1][3]));
        asm("v_cvt_pk_bf16_f32 %0, %1, %2" : "=v"(pw4) : "v"(p[2][0]), "v"(p[2][1]));
        asm("v_cvt_pk_bf16_f32 %0, %1, %2" : "=v"(pw5) : "v"(p[2][2]), "v"(p[2][3]));
        asm("v_cvt_pk_bf16_f32 %0, %1, %2" : "=v"(pw6) : "v"(p[3][0]), "v"(p[3][1]));
        asm("v_cvt_pk_bf16_f32 %0, %1, %2" : "=v"(pw7) : "v"(p[3][2]), "v"(p[3][3]));
        union { unsigned u[4]; short8 s; } pu0, pu1;
        pu0.u[0] = pw0; pu0.u[1] = pw1; pu0.u[2] = pw2; pu0.u[3] = pw3;
        pu1.u[0] = pw4; pu1.u[1] = pw5; pu1.u[2] = pw6; pu1.u[3] = pw7;

        // PV + row-sum: V fragment = one b128 under the pi layout; l via
        // mfma(P, ones) on the matrix pipe (same C/D indexing as oa).
        __builtin_amdgcn_s_setprio(1);
#pragma unroll
        for (int ks = 0; ks < 2; ++ks) {
            short8 pa = ks ? pu1.s : pu0.s;
            acc_l = __builtin_amdgcn_mfma_f32_16x16x32_bf16(pa, ones.s, acc_l, 0, 0, 0);
#pragma unroll
            for (int n = 0; n < 4; ++n) {
                int row = n*16 + lr;                    // = d
                int chunk = (ks*4 + g) ^ (row & 7);
                short8 bv = *(const short8*)(Vb + row*128 + chunk*16);
                oa[n] = __builtin_amdgcn_mfma_f32_16x16x32_bf16(pa, bv, oa[n], 0, 0, 0);
            }
        }
        __builtin_amdgcn_s_setprio(0);

        __syncthreads();   // drains vmcnt(0): next tile's stage lands here
    }
#undef STAGE

    // acc_l[r] = l for q = qw0+4g+r (same layout as oa) -> no shuffles.
#pragma unroll
    for (int r = 0; r < 4; ++r) {
        float inv = 1.0f / acc_l[r];
        int qg = qw0 + 4*g + r;
        size_t base = ((size_t)b*NC + qg)*NE + h*ND;
#pragma unroll
        for (int n = 0; n < 4; ++n)
            ctx[base + n*16 + lr] = f32_to_bf16(oa[n][r] * inv);
    }
}

extern "C" void kernel_launch(void* const* d_in, const int* in_sizes, int n_in,
                              void* d_out, int out_size, void* d_ws, size_t ws_size,
                              hipStream_t stream)
{
    const float* x    = (const float*)d_in[0];
    const void*  pad  = d_in[1];
    const float* wqkv = (const float*)d_in[2];
    const float* bqkv = (const float*)d_in[3];
    const float* wout = (const float*)d_in[4];
    const float* bout = (const float*)d_in[5];
    float* out = (float*)d_out;

    unsigned short* x_bf    = (unsigned short*)d_ws;
    unsigned short* wqkv_bf = x_bf    + 4194304;
    unsigned short* wout_bf = wqkv_bf + 3145728;
    unsigned short* qkv     = wout_bf + 1048576;
    unsigned short* ctx     = qkv     + 12582912;
    int*            lens    = (int*)(ctx + 4194304);

    fused_cast_kernel<<<8194, 256, 0, stream>>>(x, wqkv, wout, pad,
                                                x_bf, wqkv_bf, wout_bf, lens);

    gemm_qkv_kernel<<<256, 512, 0, stream>>>(x_bf, wqkv_bf, bqkv, qkv);
    attn_kernel<<<dim3(32, 32), 256, 0, stream>>>(qkv, lens, ctx);
    gemm_bt_kernel<0,64,2><<<512, 256, 0, stream>>>(ctx, wout_bf, bout,
                                                    out, nullptr, 4096, 1024, 1024);
}

// Round 2
// 90.904 us; speedup vs baseline: 1.0380x; 1.0380x over previous
//
#include <hip/hip_runtime.h>
#include <cstdint>
#include <cstddef>

typedef short short8 __attribute__((ext_vector_type(8)));
typedef float f32x4 __attribute__((ext_vector_type(4)));

#define NB 2
#define NC 2048
#define NE 1024
#define NH 16
#define ND 64
#define QSZ (NB*NH*NC*ND)   /* 4194304 elems per tensor (q, k, or v) */

typedef const __attribute__((address_space(1))) void GV;
typedef __attribute__((address_space(3))) void LV;

__device__ __forceinline__ unsigned short f32_to_bf16(float f) {
    union { float f; unsigned u; } v; v.f = f;
    return (unsigned short)((v.u + 0x7fffu + ((v.u >> 16) & 1u)) >> 16);
}

// One kernel for all preprocessing: f32->bf16 casts of x / wqkv / wout
// (8192 blocks) + per-batch pad length reduction (2 trailing blocks).
__global__ __launch_bounds__(256) void fused_cast_kernel(
    const float* __restrict__ x, const float* __restrict__ wqkv,
    const float* __restrict__ wout, const void* __restrict__ pad,
    unsigned short* __restrict__ x_bf, unsigned short* __restrict__ wqkv_bf,
    unsigned short* __restrict__ wout_bf, int* __restrict__ lengths)
{
    const int bid = blockIdx.x, tid = threadIdx.x;
    if (bid < 8192) {
        const float* src; unsigned short* dst; int i;
        if (bid < 4096)      { src = x;    dst = x_bf;    i = bid*256 + tid; }
        else if (bid < 7168) { src = wqkv; dst = wqkv_bf; i = (bid-4096)*256 + tid; }
        else                 { src = wout; dst = wout_bf; i = (bid-7168)*256 + tid; }
        float4 v = ((const float4*)src)[i];
        ushort4 o;
        o.x = f32_to_bf16(v.x); o.y = f32_to_bf16(v.y);
        o.z = f32_to_bf16(v.z); o.w = f32_to_bf16(v.w);
        ((ushort4*)dst)[i] = o;
    } else {
        // pad_mask is monotone (arange < length) -> count valids = length.
        const int b = bid - 8192;
        unsigned w0 = ((const unsigned*)pad)[0];
        int cnt = 0;
        for (int i = tid; i < NC; i += 256) {
            int idx = b*NC + i;
            bool valid;
            if (w0 == 1u)               valid = ((const int*)pad)[idx] != 0;
            else if (w0 == 0x3f800000u) valid = ((const float*)pad)[idx] != 0.0f;
            else                        valid = ((const unsigned char*)pad)[idx] != 0;
            cnt += valid ? 1 : 0;
        }
        cnt += __shfl_xor(cnt, 1);  cnt += __shfl_xor(cnt, 2);
        cnt += __shfl_xor(cnt, 4);  cnt += __shfl_xor(cnt, 8);
        cnt += __shfl_xor(cnt, 16); cnt += __shfl_xor(cnt, 32);
        __shared__ int ws_[4];
        if ((tid & 63) == 0) ws_[tid >> 6] = cnt;
        __syncthreads();
        if (tid == 0) lengths[b] = ws_[0] + ws_[1] + ws_[2] + ws_[3];
    }
}

// C = A[M,K] * Bw[N,K]^T + bias.  Tile TM x 128, BK=64, 4 waves, 16x16x32 MFMA.
// TM=128: waves 2x2 own 64x64 (QKV GEMM; launch_bounds (256,3) -> 3 blocks/CU).
// TM=64:  waves 1x4 own 64x32 (out-proj: 512 blocks -> 2/CU).
// 1-D grid with bijective XCD swizzle (nwg % 8 == 0).
// EPI=0: f32 out [M,N].
// EPI=1 (TM=128 only): bf16 scatter into qkv.  Q scaled by 0.125*log2e,
//        K: [B,H,C,HD]; V transposed [B,H,HD,C'] keys pi-permuted per 64-tile
//        so attention's PV B-fragment is one conflict-free b128.
//        Pad-length skip: attention never reads K rows / V cols at token
//        index >= roundup64(len_b) (tiles beyond nt untouched; partial-tile
//        masked keys get p=0 without consuming the score), so K/V blocks
//        entirely beyond roundup64(len_b) early-exit.  Rows in
//        [len, roundup64(len)) live in a non-skipped tile -> no poisoned
//        value ever reaches an MFMA.
template<int EPI, int TM, int WPE>
__global__ __launch_bounds__(256, WPE) void gemm_bt_kernel(
    const unsigned short* __restrict__ A,
    const unsigned short* __restrict__ Bw,
    const float* __restrict__ bias,
    const int* __restrict__ lengths,
    float* __restrict__ outF,
    unsigned short* __restrict__ outQ,
    int M, int N, int K)
{
    constexpr int NF = (TM == 128) ? 4 : 2;       // n-frags per wave
    constexpr int WCW = 16 * NF;                  // cols per wave
    __shared__ unsigned short As[TM*64];
    __shared__ unsigned short Bs[128*64];
    const int tid = threadIdx.x;
    const int w = tid >> 6, lane = tid & 63;
    const int wr = (TM == 128) ? (w >> 1) : 0;
    const int wc = (TM == 128) ? (w & 1) : w;
    const int g = lane >> 4, lr = lane & 15;
    const int nbx = N >> 7, nwg = gridDim.x;
    const int id = blockIdx.x;
    const int swz = (id & 7) * (nwg >> 3) + (id >> 3);
    const int mBase = (swz / nbx) * TM, nBase = (swz % nbx) * 128;

    if constexpr (EPI == 1) {
        if (nBase >= 1024) {                       // K or V columns only
            const int lb = lengths[mBase >> 11];   // batch = mBase / 2048
            if ((mBase & 2047) >= ((lb + 63) & ~63)) return;
        }
    }

    f32x4 acc[4][NF];
#pragma unroll
    for (int m = 0; m < 4; ++m)
#pragma unroll
        for (int n = 0; n < NF; ++n) acc[m][n] = (f32x4){0.f, 0.f, 0.f, 0.f};

    constexpr int AJ = TM / 32;                   // A staging instrs (1KB each)
    int srow[4], scol[4]; unsigned ldso[4];
#pragma unroll
    for (int j = 0; j < 4; ++j) {
        int o = ((j*4 + w) << 10) + lane*16;
        int row = o >> 7;
        int chunk = ((o >> 4) & 7) ^ (row & 7);
        srow[j] = row; scol[j] = chunk * 8; ldso[j] = (unsigned)((j*4 + w) << 10);
    }

    const int nk = K >> 6;
    for (int kt = 0; kt < nk; ++kt) {
        const int k0 = kt << 6;
#pragma unroll
        for (int j = 0; j < AJ; ++j) {
            const unsigned short* ga = A + (size_t)(mBase + srow[j])*K + (k0 + scol[j]);
            __builtin_amdgcn_global_load_lds((GV*)ga, (LV*)((char*)As + ldso[j]), 16, 0, 0);
        }
#pragma unroll
        for (int j = 0; j < 4; ++j) {
            const unsigned short* gb = Bw + (size_t)(nBase + srow[j])*K + (k0 + scol[j]);
            __builtin_amdgcn_global_load_lds((GV*)gb, (LV*)((char*)Bs + ldso[j]), 16, 0, 0);
        }
        __syncthreads();
#pragma unroll
        for (int ks = 0; ks < 2; ++ks) {
            short8 af[4], bf[NF];
#pragma unroll
            for (int m = 0; m < 4; ++m) {
                int row = wr*64 + m*16 + lr;
                int chunk = (ks*4 + g) ^ (row & 7);
                af[m] = *(const short8*)((const char*)As + row*128 + chunk*16);
            }
#pragma unroll
            for (int n = 0; n < NF; ++n) {
                int row = wc*WCW + n*16 + lr;
                int chunk = (ks*4 + g) ^ (row & 7);
                bf[n] = *(const short8*)((const char*)Bs + row*128 + chunk*16);
            }
#pragma unroll
            for (int m = 0; m < 4; ++m)
#pragma unroll
                for (int n = 0; n < NF; ++n)
                    acc[m][n] = __builtin_amdgcn_mfma_f32_16x16x32_bf16(af[m], bf[n], acc[m][n], 0, 0, 0);
        }
        __syncthreads();
    }

    // Epilogue.  C/D layout: col = lane&15, row = 4*(lane>>4)+reg.
    if constexpr (EPI == 0) {
#pragma unroll
        for (int n = 0; n < NF; ++n) {
            int col = nBase + wc*WCW + n*16 + lr;
            float bv = bias[col];
#pragma unroll
            for (int m = 0; m < 4; ++m) {
                int rowb = mBase + wr*64 + m*16 + 4*g;
#pragma unroll
                for (int r = 0; r < 4; ++r)
                    outF[(size_t)(rowb + r)*N + col] = acc[m][n][r] + bv;
            }
        }
    } else {
        if (nBase >= 2048) {
            // V path: pi-permuted transposed layout, 8B packed stores.
#pragma unroll
            for (int n = 0; n < NF; ++n) {
                int col = nBase + wc*WCW + n*16 + lr;
                float bv = bias[col];
                int hh = (col >> 6) & 15, d = col & 63;
#pragma unroll
                for (int m = 0; m < 4; ++m) {
                    int rowb = mBase + wr*64 + m*16 + 4*g;     // token index, r=0
                    int bb = rowb >> 11, c = rowb & 2047;
                    int cp = (c & ~63) | ((m >> 1) << 5) | (g << 3) | ((m & 1) << 2);
                    size_t base = (((size_t)((4 + bb)*16 + hh))*64 + d)*2048 + cp;
                    float v0 = acc[m][n][0] + bv, v1 = acc[m][n][1] + bv;
                    float v2 = acc[m][n][2] + bv, v3 = acc[m][n][3] + bv;
                    unsigned w0, w1;
                    asm("v_cvt_pk_bf16_f32 %0, %1, %2" : "=v"(w0) : "v"(v0), "v"(v1));
                    asm("v_cvt_pk_bf16_f32 %0, %1, %2" : "=v"(w1) : "v"(v2), "v"(v3));
                    union { unsigned u[2]; uint2 v; } pk2; pk2.u[0] = w0; pk2.u[1] = w1;
                    *(uint2*)(outQ + base) = pk2.v;
                }
            }
        } else {
            // Q/K path (Q pre-scaled into exp2 domain: 0.125 * log2(e)).
#pragma unroll
            for (int n = 0; n < NF; ++n) {
                int col = nBase + wc*WCW + n*16 + lr;
                float bv = bias[col];
                int t = col >> 10, hh = (col >> 6) & 15, d = col & 63;
                float qscale = (t == 0) ? 0.1803368801f : 1.0f;
#pragma unroll
                for (int m = 0; m < 4; ++m) {
                    int rowb = mBase + wr*64 + m*16 + 4*g;
#pragma unroll
                    for (int r = 0; r < 4; ++r) {
                        int row = rowb + r;               // = b*NC + c
                        int bb = row >> 11, c = row & 2047;
                        unsigned short bf16v = f32_to_bf16((acc[m][n][r] + bv) * qscale);
                        size_t idx = ((((size_t)(t*2 + bb))*16 + hh)*2048 + c)*64 + d;
                        outQ[idx] = bf16v;
                    }
                }
            }
        }
    }
}

// Flash attention, causal, swapped-QK^T (one q-row per lane), in-register P.
// One q-tile per block; 1024 blocks = 4/CU; qb<->y permutation gives constant
// per-CU-quad work.  Row-sum l computed ON THE MFMA PIPE via mfma(P, ones) --
// acc_l[r] lands in the same C/D indexing as oa (row 4g+r), so no shuffles,
// no per-tile VALU adds.  No exp clamp (scores are bounded dot-products).
__global__ __launch_bounds__(256, 4) void attn_kernel(
    const unsigned short* __restrict__ qkv,
    const int* __restrict__ lengths,
    unsigned short* __restrict__ ctx)
{
    __shared__ unsigned short Kt[2][64*64];
    __shared__ unsigned short Vt[2][64*64];
    const int bh = blockIdx.x;
    const int b = bh >> 4, h = bh & 15;
    const int y = blockIdx.y;
    const int qb = (y < 8) ? 31 - y : (y < 16) ? y - 8 : (y < 24) ? 39 - y : y - 16;
    const int q0 = qb * 64;
    const int len = lengths[b];
    const int nt = min(qb + 1, (len + 63) >> 6);
    const int tid = threadIdx.x, w = tid >> 6, lane = tid & 63;
    const int g = lane >> 4, lr = lane & 15;
    const unsigned short* qp = qkv +          ((size_t)(b*NH + h))*NC*ND;
    const unsigned short* kp = qkv + QSZ    + ((size_t)(b*NH + h))*NC*ND;
    const unsigned short* vp = qkv + 2*QSZ  + ((size_t)(b*NH + h))*ND*NC;  // [d][c-perm]
    const int qw0 = q0 + w*16;

    short8 aq[2];
#pragma unroll
    for (int ks = 0; ks < 2; ++ks)
        aq[ks] = *(const short8*)(qp + (size_t)(qw0 + lr)*ND + ks*32 + 8*g);

    f32x4 oa[4];
#pragma unroll
    for (int n = 0; n < 4; ++n) oa[n] = (f32x4){0.f, 0.f, 0.f, 0.f};
    f32x4 acc_l = (f32x4){0.f, 0.f, 0.f, 0.f};
    union { unsigned u[4]; short8 s; } ones;
    ones.u[0] = ones.u[1] = ones.u[2] = ones.u[3] = 0x3F803F80u;   // bf16 1.0 x8

    // staging geometry (per-lane invariant)
    int srw[2], sck[2]; unsigned ldso[2];
#pragma unroll
    for (int j = 0; j < 2; ++j) {
        int o = ((j*4 + w) << 10) + lane*16;
        int row = o >> 7;
        int chunk = ((o >> 4) & 7) ^ (row & 7);
        srw[j] = row; sck[j] = chunk * 8; ldso[j] = (unsigned)((j*4 + w) << 10);
    }

#define STAGE(T, BUF) do {                                                        \
    int k0s = (T) << 6;                                                           \
    _Pragma("unroll")                                                             \
    for (int j = 0; j < 2; ++j) {                                                 \
        const unsigned short* gk = kp + (size_t)(k0s + srw[j])*ND + sck[j];       \
        const unsigned short* gv = vp + (size_t)srw[j]*NC + k0s + sck[j];         \
        __builtin_amdgcn_global_load_lds((GV*)gk, (LV*)((char*)Kt[BUF] + ldso[j]), 16, 0, 0); \
        __builtin_amdgcn_global_load_lds((GV*)gv, (LV*)((char*)Vt[BUF] + ldso[j]), 16, 0, 0); \
    } } while (0)

    STAGE(0, 0);
    __syncthreads();

#pragma unroll 2
    for (int t = 0; t < nt; ++t) {
        if (t + 1 < nt) STAGE(t + 1, (t + 1) & 1);
        const char* Kb = (const char*)Kt[t & 1];
        const char* Vb = (const char*)Vt[t & 1];
        const int k0 = t << 6;

        // S^T: mfma(A=K, B=Q).  sa[a][r] = S[key=k0+16a+4g+r][q=qw0+lr]
        f32x4 sa[4];
#pragma unroll
        for (int a = 0; a < 4; ++a) sa[a] = (f32x4){0.f, 0.f, 0.f, 0.f};
        __builtin_amdgcn_s_setprio(1);
#pragma unroll
        for (int ks = 0; ks < 2; ++ks) {
#pragma unroll
            for (int a = 0; a < 4; ++a) {
                int row = a*16 + lr;
                int chunk = (ks*4 + g) ^ (row & 7);
                short8 ak = *(const short8*)(Kb + row*128 + chunk*16);
                sa[a] = __builtin_amdgcn_mfma_f32_16x16x32_bf16(ak, aq[ks], sa[a], 0, 0, 0);
            }
        }
        __builtin_amdgcn_s_setprio(0);

        // no-max softmax in exp2 domain (no clamp: scores are bounded)
        float p[4][4];
        const bool edge = (t == nt - 1);
        if (!edge) {
#pragma unroll
            for (int a = 0; a < 4; ++a)
#pragma unroll
                for (int r = 0; r < 4; ++r)
                    p[a][r] = exp2f(sa[a][r]);
        } else {
            const int qg = qw0 + lr;
            const int kb0 = k0 + 4*g;
#pragma unroll
            for (int a = 0; a < 4; ++a)
#pragma unroll
                for (int r = 0; r < 4; ++r) {
                    int key = kb0 + 16*a + r;
                    p[a][r] = (key <= qg && key < len) ? exp2f(sa[a][r]) : 0.f;
                }
        }

        // pack P to bf16 fragments in-register (kappa ordering)
        unsigned pw0, pw1, pw2, pw3, pw4, pw5, pw6, pw7;
        asm("v_cvt_pk_bf16_f32 %0, %1, %2" : "=v"(pw0) : "v"(p[0][0]), "v"(p[0][1]));
        asm("v_cvt_pk_bf16_f32 %0, %1, %2" : "=v"(pw1) : "v"(p[0][2]), "v"(p[0][3]));
        asm("v_cvt_pk_bf16_f32 %0, %1, %2" : "=v"(pw2) : "v"(p[1][0]), "v"(p[1][1]));
        asm("v_cvt_pk_bf16_f32 %0, %1, %2" : "=v"(pw3) : "v"(p[1][2]), "v"(p[1][3]));
        asm("v_cvt_pk_bf16_f32 %0, %1, %2" : "=v"(pw4) : "v"(p[2][0]), "v"(p[2][1]));
        asm("v_cvt_pk_bf16_f32 %0, %1, %2" : "=v"(pw5) : "v"(p[2][2]), "v"(p[2][3]));
        asm("v_cvt_pk_bf16_f32 %0, %1, %2" : "=v"(pw6) : "v"(p[3][0]), "v"(p[3][1]));
        asm("v_cvt_pk_bf16_f32 %0, %1, %2" : "=v"(pw7) : "v"(p[3][2]), "v"(p[3][3]));
        union { unsigned u[4]; short8 s; } pu0, pu1;
        pu0.u[0] = pw0; pu0.u[1] = pw1; pu0.u[2] = pw2; pu0.u[3] = pw3;
        pu1.u[0] = pw4; pu1.u[1] = pw5; pu1.u[2] = pw6; pu1.u[3] = pw7;

        // PV + row-sum: V fragment = one b128 under the pi layout; l via
        // mfma(P, ones) on the matrix pipe (same C/D indexing as oa).
        __builtin_amdgcn_s_setprio(1);
#pragma unroll
        for (int ks = 0; ks < 2; ++ks) {
            short8 pa = ks ? pu1.s : pu0.s;
            acc_l = __builtin_amdgcn_mfma_f32_16x16x32_bf16(pa, ones.s, acc_l, 0, 0, 0);
#pragma unroll
            for (int n = 0; n < 4; ++n) {
                int row = n*16 + lr;                    // = d
                int chunk = (ks*4 + g) ^ (row & 7);
                short8 bv = *(const short8*)(Vb + row*128 + chunk*16);
                oa[n] = __builtin_amdgcn_mfma_f32_16x16x32_bf16(pa, bv, oa[n], 0, 0, 0);
            }
        }
        __builtin_amdgcn_s_setprio(0);

        __syncthreads();   // drains vmcnt(0): next tile's stage lands here
    }
#undef STAGE

    // acc_l[r] = l for q = qw0+4g+r (same layout as oa) -> no shuffles.
#pragma unroll
    for (int r = 0; r < 4; ++r) {
        float inv = 1.0f / acc_l[r];
        int qg = qw0 + 4*g + r;
        size_t base = ((size_t)b*NC + qg)*NE + h*ND;
#pragma unroll
        for (int n = 0; n < 4; ++n)
            ctx[base + n*16 + lr] = f32_to_bf16(oa[n][r] * inv);
    }
}

extern "C" void kernel_launch(void* const* d_in, const int* in_sizes, int n_in,
                              void* d_out, int out_size, void* d_ws, size_t ws_size,
                              hipStream_t stream)
{
    const float* x    = (const float*)d_in[0];
    const void*  pad  = d_in[1];
    const float* wqkv = (const float*)d_in[2];
    const float* bqkv = (const float*)d_in[3];
    const float* wout = (const float*)d_in[4];
    const float* bout = (const float*)d_in[5];
    float* out = (float*)d_out;

    unsigned short* x_bf    = (unsigned short*)d_ws;
    unsigned short* wqkv_bf = x_bf    + 4194304;
    unsigned short* wout_bf = wqkv_bf + 3145728;
    unsigned short* qkv     = wout_bf + 1048576;
    unsigned short* ctx     = qkv     + 12582912;
    int*            lens    = (int*)(ctx + 4194304);

    fused_cast_kernel<<<8194, 256, 0, stream>>>(x, wqkv, wout, pad,
                                                x_bf, wqkv_bf, wout_bf, lens);

    gemm_bt_kernel<1,128,3><<<768, 256, 0, stream>>>(x_bf, wqkv_bf, bqkv, lens,
                                                     nullptr, qkv, 4096, 3072, 1024);
    attn_kernel<<<dim3(32, 32), 256, 0, stream>>>(qkv, lens, ctx);
    gemm_bt_kernel<0,64,2><<<512, 256, 0, stream>>>(ctx, wout_bf, bout, nullptr,
                                                    out, nullptr, 4096, 1024, 1024);
}